// Round 3
// baseline (28.788 us; speedup 1.0000x reference)
//
#include <hip/hip_runtime.h>
#include <stdint.h>

#define ETA    3.0f
#define KCAP   96
#define POS_W  1.2f
#define NG     64
#define BATCH  4
#define HH     192
#define WW     192
#define NCELL  (HH*WW)
#define NCLS   4
#define CAP    4096
#define PTHR   256
#define NWAVE  4
#define NBLK   (BATCH*NG)          /* 256 blocks total */
#define SEGS   16                  /* resolve segments per batch */
#define NB2    (BATCH*SEGS)        /* 64 resolve jobs */
#define SEGC   (NCELL/SEGS)        /* 2304 cells per segment */
#define BCLAIM (NG*KCAP)           /* 6144 claim slots per batch */
#define INF64  0xFFFFFFFFFFFFFFFFull
#define TOPBIT 0x8000000000000000ull
#define FSET   0x5EC0DE5Au         /* flag "set" magic; cleared to 0 at end */

/* ws layout — NO init required ever:
   flags follow a set(FSET)/clear(0) lifecycle; block 0 clears after the
   final reduce (no block can still be spinning then). First call sees
   poison != FSET => "not set". Replays see 0 => "not set".
   [WS_PDONE] pdone u32[NBLK]     per-pair publish flags
   [WS_RDONE] rdone u32[NB2]      per-resolve-job publish flags
   [WS_CCNT]  ccnt  u32[NBLK]     per-pair claim counts (data, fence-covered)
   [WS_PA]    pA float4[NBLK]     (reg, obj_base) partials
   [WS_PC]    pC float4[NB2]      (obj_corr, lse, picked) partials
   [WS_CLAIM] claims u64[NBLK*KCAP]  (dist_bits<<32)|n                    */
#define WS_PDONE 0
#define WS_RDONE 1024
#define WS_CCNT  1280
#define WS_PA    2304
#define WS_PC    6400
#define WS_CLAIM 7424

#define OBJ4_PER_BLK 144   /* (B*NCELL floats / 4) / NBLK */

__device__ __forceinline__ float log_sigmoid(float x) {
    return fminf(x, 0.0f) - __logf(1.0f + __expf(-fabsf(x)));
}

__device__ __forceinline__ float segsq(float wx, float wy, float vx, float vy, float inv) {
    float t = (wx * vx + wy * vy) * inv;
    t = fminf(fmaxf(t, 0.0f), 1.0f);
    float dx = wx - t * vx;
    float dy = wy - t * vy;
    return dx * dx + dy * dy;
}

__device__ __forceinline__ unsigned aload(const unsigned* p) {
    return __hip_atomic_load(p, __ATOMIC_RELAXED, __HIP_MEMORY_SCOPE_AGENT);
}
__device__ __forceinline__ void astore(unsigned* p, unsigned v) {
    __hip_atomic_store(p, v, __ATOMIC_RELAXED, __HIP_MEMORY_SCOPE_AGENT);
}

/* 5-float deterministic block reduction; result valid on tid 0 (in place) */
__device__ __forceinline__ void block_red5(float v[5], float* sbuf) {
    #pragma unroll
    for (int off = 32; off > 0; off >>= 1) {
        #pragma unroll
        for (int q = 0; q < 5; ++q) v[q] += __shfl_down(v[q], off);
    }
    const int lane = threadIdx.x & 63;
    const int wid  = threadIdx.x >> 6;
    __syncthreads();
    if (lane == 0) {
        #pragma unroll
        for (int q = 0; q < 5; ++q) sbuf[wid * 5 + q] = v[q];
    }
    __syncthreads();
    if (threadIdx.x == 0) {
        #pragma unroll
        for (int q = 0; q < 5; ++q) {
            float r = 0.0f;
            #pragma unroll
            for (int w = 0; w < NWAVE; ++w) r += sbuf[w * 5 + q];
            v[q] = r;
        }
    }
}

__global__ __launch_bounds__(PTHR)
void fused_kernel(const float* __restrict__ pred_reg,
                  const float* __restrict__ pred_obj,
                  const float* __restrict__ pred_cls,
                  const float* __restrict__ gt_pts,
                  const int*   __restrict__ gt_lbl,
                  const int*   __restrict__ stride_p,
                  unsigned* pdone, unsigned* rdone, unsigned* ccnt_g,
                  float4* pA, float4* pC,
                  unsigned long long* claims,
                  float* out)
{
    const int pair = blockIdx.x;          // b*NG + g
    const int b    = pair >> 6;
    const int tid  = threadIdx.x;
    const int lane = tid & 63;
    const int wid  = tid >> 6;
    const float s  = (float)(*stride_p);

    /* pair phase and resolve phase are strictly sequential -> union LDS */
    __shared__ union {
        struct { unsigned long long keys[CAP]; int hist[PTHR]; } p;           /* 33 KB */
        struct { unsigned long long cl[BCLAIM]; unsigned table[SEGC]; int cnts[NG]; } r; /* 57.5 KB */
    } U;
    __shared__ float sbuf[NWAVE * 5];
    __shared__ int   wsum[NWAVE];
    __shared__ int   scnt, ccl, sd, sp;

    /* ================= pair phase (math identical to round 2) ============ */
    float c_obj = 0.0f;
    if (tid < OBJ4_PER_BLK) {
        const float4 v = ((const float4*)pred_obj)[pair * OBJ4_PER_BLK + tid];
        c_obj = -log_sigmoid(-v.x) - log_sigmoid(-v.y)
                - log_sigmoid(-v.z) - log_sigmoid(-v.w);
    }

    const float* gp = gt_pts + (size_t)pair * 6;
    const float Ax = gp[0], Ay = gp[1];
    const float Bx = gp[2], By = gp[3];
    const float Cx = gp[4], Cy = gp[5];

    const float vABx = Bx - Ax, vABy = By - Ay;
    const float vBCx = Cx - Bx, vBCy = Cy - By;
    const float vCAx = Ax - Cx, vCAy = Ay - Cy;
    const float invAB = 1.0f / (vABx * vABx + vABy * vABy + 1e-9f);
    const float invBC = 1.0f / (vBCx * vBCx + vBCy * vBCy + 1e-9f);
    const float invCA = 1.0f / (vCAx * vCAx + vCAy * vCAy + 1e-9f);

    const float xmin = fminf(Ax, fminf(Bx, Cx)) - ETA;
    const float xmax = fmaxf(Ax, fmaxf(Bx, Cx)) + ETA;
    const float ymin = fminf(Ay, fminf(By, Cy)) - ETA;
    const float ymax = fmaxf(Ay, fmaxf(By, Cy)) + ETA;
    const float inv_sf = 1.0f / s;
    int j0 = max(0,      (int)floorf(xmin * inv_sf - 0.5f) - 1);
    int j1 = min(WW - 1, (int)ceilf (xmax * inv_sf - 0.5f) + 1);
    int i0 = max(0,      (int)floorf(ymin * inv_sf - 0.5f) - 1);
    int i1 = min(HH - 1, (int)ceilf (ymax * inv_sf - 0.5f) + 1);
    const int nbw = j1 - j0 + 1;
    const int nbh = i1 - i0 + 1;
    const int nb  = (nbw > 0 && nbh > 0) ? nbw * nbh : 0;

    if (tid == 0) { scnt = 0; ccl = 0; }
    __syncthreads();

    for (int t = tid; t < nb; t += PTHR) {
        const int li = t / nbw;
        const int lj = t - li * nbw;
        const int i = i0 + li;
        const int j = j0 + lj;
        const float px = ((float)j + 0.5f) * s;
        const float py = ((float)i + 0.5f) * s;

        const float d1 = (px - Bx) * (Ay - By) - (Ax - Bx) * (py - By);
        const float d2 = (px - Cx) * (By - Cy) - (Bx - Cx) * (py - Cy);
        const float d3 = (px - Ax) * (Cy - Ay) - (Cx - Ax) * (py - Ay);
        const bool has_neg = (d1 < 0.0f) | (d2 < 0.0f) | (d3 < 0.0f);
        const bool has_pos = (d1 > 0.0f) | (d2 > 0.0f) | (d3 > 0.0f);
        const bool inside = !(has_neg && has_pos);

        float dsq = segsq(px - Ax, py - Ay, vABx, vABy, invAB);
        dsq = fminf(dsq, segsq(px - Bx, py - By, vBCx, vBCy, invBC));
        dsq = fminf(dsq, segsq(px - Cx, py - Cy, vCAx, vCAy, invCA));
        const float dist = sqrtf(dsq + 1e-12f);

        if (inside || dist <= ETA) {
            int slot = atomicAdd(&scnt, 1);
            if (slot < CAP) {
                const int n = i * WW + j;
                U.p.keys[slot] = (((unsigned long long)__float_as_uint(dist)) << 16) | (unsigned)n;
            }
        }
    }
    __syncthreads();

    const int M = min(scnt, CAP);
    unsigned long long T = INF64;

    if (M > KCAP) {
        /* exact 48-bit radix select of the KCAP-th smallest key */
        unsigned long long prefix = 0;
        int need = KCAP;
        for (int shift = 40; shift >= 0; shift -= 8) {
            U.p.hist[tid] = 0;
            __syncthreads();
            for (int t = tid; t < M; t += PTHR) {
                const unsigned long long k = U.p.keys[t];
                if ((k >> (shift + 8)) == prefix)
                    atomicAdd(&U.p.hist[(int)((k >> shift) & 0xFF)], 1);
            }
            __syncthreads();
            const int h = U.p.hist[tid];
            int incl = h;
            #pragma unroll
            for (int off = 1; off < 64; off <<= 1) {
                const int o = __shfl_up(incl, off);
                if (lane >= off) incl += o;
            }
            if (lane == 63) wsum[wid] = incl;
            __syncthreads();
            #pragma unroll
            for (int w = 0; w < NWAVE; ++w) if (w < wid) incl += wsum[w];
            const int excl = incl - h;
            if (excl < need && incl >= need) { sd = tid; sp = excl; }
            __syncthreads();
            prefix = (prefix << 8) | (unsigned)sd;
            need  -= sp;
            __syncthreads();
        }
        T = prefix;   // exactly KCAP keys <= T
    }

    /* claim emit + reg loss */
    float c_reg = 0.0f;
    for (int t = tid; t < M; t += PTHR) {
        const unsigned long long k = U.p.keys[t];
        if (k > T) continue;
        const int n = (int)(k & 0xFFFFull);

        const int slot = atomicAdd(&ccl, 1);
        if (slot < KCAP)
            claims[(size_t)pair * KCAP + slot] =
                ((k >> 16) << 32) | (unsigned long long)(unsigned)n;

        const int i = n / WW;
        const int j = n - i * WW;
        const float ax = ((float)j + 0.5f) * s;
        const float ay = ((float)i + 0.5f) * s;

        const float g0x = (Ax - ax) * inv_sf, g0y = (Ay - ay) * inv_sf;
        const float g1x = (Bx - ax) * inv_sf, g1y = (By - ay) * inv_sf;
        const float g2x = (Cx - ax) * inv_sf, g2y = (Cy - ay) * inv_sf;

        const float* pr = pred_reg + (size_t)b * 6 * NCELL + n;
        const float p0x = pr[0 * NCELL], p0y = pr[1 * NCELL];
        const float p1x = pr[2 * NCELL], p1y = pr[3 * NCELL];
        const float p2x = pr[4 * NCELL], p2y = pr[5 * NCELL];

        c_reg += (p0x - g0x) * (p0x - g0x) + (p0y - g0y) * (p0y - g0y);

        const float d11 = sqrtf((p1x - g1x) * (p1x - g1x) + (p1y - g1y) * (p1y - g1y) + 1e-12f);
        const float d12 = sqrtf((p1x - g2x) * (p1x - g2x) + (p1y - g2y) * (p1y - g2y) + 1e-12f);
        const float d21 = sqrtf((p2x - g1x) * (p2x - g1x) + (p2y - g1y) * (p2y - g1y) + 1e-12f);
        const float d22 = sqrtf((p2x - g2x) * (p2x - g2x) + (p2y - g2y) * (p2y - g2y) + 1e-12f);

        c_reg += fminf(d11, d12) + fminf(d21, d22)
               + fminf(d11, d21) + fminf(d12, d22);
    }
    __syncthreads();   // ccl final; all claim stores drained (vmcnt0 at barrier)
    if (tid == 0) ccnt_g[pair] = (unsigned)min(ccl, KCAP);

    {
        float v5[5] = { c_reg, c_obj, 0.0f, 0.0f, 0.0f };
        block_red5(v5, sbuf);
        if (tid == 0) {
            pA[pair] = make_float4(v5[0], v5[1], 0.0f, 0.0f);
            __threadfence();              /* release: claims/ccnt/pA -> coherent */
            astore(&pdone[pair], FSET);   /* publish */
        }
    }

    /* ================= resolve phase: blocks b*64+k, k<SEGS ============== */
    if ((pair & 63) < SEGS) {
        const int seg = pair & 63;
        const int n0  = seg * SEGC;

        __syncthreads();   /* union repurpose; own pdone already set */

        /* wait for all 64 pairs of my batch (lane l watches pair b*64+l) */
        if (wid == 0) {
            for (;;) {
                const unsigned f = aload(&pdone[(b << 6) + lane]);
                if (__all(f == FSET)) break;
                __builtin_amdgcn_s_sleep(2);
            }
        }
        __syncthreads();
        __threadfence();   /* acquire: invalidate caches before reading claims */

        if (tid < NG) U.r.cnts[tid] = (int)ccnt_g[(b << 6) + tid];
        for (int i = tid; i < SEGC; i += PTHR) U.r.table[i] = 0xFFFFFFFFu;
        if (tid == 0) ccl = 0;
        __syncthreads();

        /* pass 1: compact my-segment claims into LDS + exact dist atomicMin */
        const unsigned long long* bcl = claims + (size_t)b * BCLAIM;
        for (int sIdx = tid; sIdx < BCLAIM; sIdx += PTHR) {
            const int pg = sIdx / KCAP;
            const int r  = sIdx - pg * KCAP;
            if (r < U.r.cnts[pg]) {
                const unsigned long long e = bcl[sIdx];
                const int ln = (int)(e & 0xFFFFull) - n0;
                if ((unsigned)ln < (unsigned)SEGC) {
                    const int i = atomicAdd(&ccl, 1);
                    U.r.cl[i] = e | ((unsigned long long)pg << 16);
                    atomicMin(&U.r.table[ln], (unsigned)(e >> 32));
                }
            }
        }
        __syncthreads();
        const int NC = ccl;

        /* pass 2a: mark dist-winners while table holds dists */
        for (int i = tid; i < NC; i += PTHR) {
            const unsigned long long e = U.r.cl[i];
            const int ln = (int)(e & 0xFFFFull) - n0;
            if (U.r.table[ln] == (unsigned)(e >> 32)) U.r.cl[i] = e | TOPBIT;
        }
        __syncthreads();
        /* pass 2b: tie-break by g (g<64 < any dist bits since dist>=1e-6) */
        for (int i = tid; i < NC; i += PTHR) {
            const unsigned long long e = U.r.cl[i];
            if (e & TOPBIT) {
                const int ln = (int)(e & 0xFFFFull) - n0;
                atomicMin(&U.r.table[ln], (unsigned)((e >> 16) & 63ull));
            }
        }
        __syncthreads();

        /* pass 3: unique winners compute obj-correction, lse, picked */
        float v[5] = { 0.0f, 0.0f, 0.0f, 0.0f, 0.0f };
        const size_t bc = (size_t)b * NCLS * NCELL;
        for (int i = tid; i < NC; i += PTHR) {
            const unsigned long long e = U.r.cl[i];
            if (!(e & TOPBIT)) continue;
            const int n = (int)(e & 0xFFFFull);
            const int g = (int)((e >> 16) & 63ull);
            if (U.r.table[n - n0] != (unsigned)g) continue;

            const float x = pred_obj[b * NCELL + n];
            v[0] += (-POS_W * log_sigmoid(x)) + log_sigmoid(-x);

            const float* pc = pred_cls + bc + n;
            const float l0 = pc[0];
            const float l1 = pc[NCELL];
            const float l2 = pc[2 * NCELL];
            const float l3 = pc[3 * NCELL];
            const float m = fmaxf(fmaxf(l0, l1), fmaxf(l2, l3));
            v[1] += m + __logf(__expf(l0 - m) + __expf(l1 - m)
                             + __expf(l2 - m) + __expf(l3 - m));
            const int tgt = gt_lbl[b * NG + g];
            v[2] += (tgt == 0) ? l0 : (tgt == 1) ? l1 : (tgt == 2) ? l2 : l3;
        }
        block_red5(v, sbuf);
        if (tid == 0) {
            pC[(b << 4) + seg] = make_float4(v[0], v[1], v[2], 0.0f);
            __threadfence();                      /* release pC */
            astore(&rdone[(b << 4) + seg], FSET); /* publish */
        }

        /* ============ final phase: block 0 reduces everything ============ */
        if (pair == 0) {
            __syncthreads();
            if (wid == 0) {
                for (;;) {
                    const unsigned f = aload(&rdone[lane]);   /* NB2 == 64 */
                    if (__all(f == FSET)) break;
                    __builtin_amdgcn_s_sleep(2);
                }
            }
            __syncthreads();
            __threadfence();   /* acquire; rdone chain makes pA/pC visible */

            const float4 a = pA[tid];              /* NBLK == PTHR */
            float4 c = make_float4(0.f, 0.f, 0.f, 0.f);
            if (tid < NB2) c = pC[tid];
            float w5[5] = { a.x, a.y, c.x, c.y, c.z };
            block_red5(w5, sbuf);
            if (tid == 0) {
                out[0] = w5[0];               /* reg */
                out[1] = w5[1] + w5[2];       /* obj base + corrections */
                out[2] = w5[3] - w5[4];       /* lse - picked */
            }

            /* clear flags for the next call/replay; nobody is spinning now */
            if (tid < NBLK) astore(&pdone[tid], 0u);
            if (tid < NB2)  astore(&rdone[tid], 0u);
        }
    }
}

extern "C" void kernel_launch(void* const* d_in, const int* in_sizes, int n_in,
                              void* d_out, int out_size, void* d_ws, size_t ws_size,
                              hipStream_t stream) {
    const float* pred_reg = (const float*)d_in[0];
    const float* pred_obj = (const float*)d_in[1];
    const float* pred_cls = (const float*)d_in[2];
    const float* gt_pts   = (const float*)d_in[3];
    const int*   gt_lbl   = (const int*)d_in[4];
    const int*   stride_p = (const int*)d_in[5];
    float* out = (float*)d_out;

    char* ws = (char*)d_ws;
    unsigned* pdone = (unsigned*)(ws + WS_PDONE);
    unsigned* rdone = (unsigned*)(ws + WS_RDONE);
    unsigned* ccnt  = (unsigned*)(ws + WS_CCNT);
    float4*   pA    = (float4*)(ws + WS_PA);
    float4*   pC    = (float4*)(ws + WS_PC);
    unsigned long long* claims = (unsigned long long*)(ws + WS_CLAIM);

    (void)in_sizes; (void)n_in; (void)ws_size; (void)out_size;

    hipLaunchKernelGGL(fused_kernel, dim3(NBLK), dim3(PTHR), 0, stream,
                       pred_reg, pred_obj, pred_cls, gt_pts, gt_lbl, stride_p,
                       pdone, rdone, ccnt, pA, pC, claims, out);
}

// Round 4
// 23.319 us; speedup vs baseline: 1.2345x; 1.2345x over previous
//
#include <hip/hip_runtime.h>
#include <stdint.h>

#define ETA    3.0f
#define KCAP   96
#define POS_W  1.2f
#define NG     64
#define BATCH  4
#define HH     192
#define WW     192
#define NCELL  (HH*WW)
#define NCLS   4
#define CAP    4096
#define PTHR   256
#define NWAVE  4
#define NBLK   (BATCH*NG)          /* 256 pair blocks */
#define SEGS   32                  /* row segments per batch in resolve */
#define NB2    (BATCH*SEGS)        /* 128 resolve blocks */
#define SEGC   (NCELL/SEGS)        /* 1152 cells (6 rows) per segment */
#define BCLAIM (NG*KCAP)           /* 6144 claim slots per batch */
#define INF64  0xFFFFFFFFFFFFFFFFull
#define TOPBIT 0x8000000000000000ull

/* ws layout (NO host-side init; arrival init'd by pair_kernel block 0):
   [0]        arrival int
   [WS_CCNT]  ccnt  u32[NBLK]           per-pair claim counts
   [WS_MASK]  smask u32[NBLK]           per-pair segment bitmask (SEGS=32)
   [WS_CLAIM] claims u64[NBLK*KCAP]     (dist_bits<<32)|n
   [WS_PA]    pA float4[NBLK]           (reg, obj_base) partials
   [WS_PC]    pC float4[NB2]            (obj_corr, lse, picked) partials */
#define WS_CCNT  16
#define WS_MASK  (WS_CCNT + NBLK*4)          /* 1040 */
#define WS_CLAIM (WS_MASK + NBLK*4)          /* 2064 (8-aligned) */
#define WS_PA    (WS_CLAIM + NBLK*KCAP*8)    /* 198672 (16-aligned) */
#define WS_PC    (WS_PA + NBLK*16)

#define OBJ4_PER_BLK 144   /* (B*NCELL floats / 4) / NBLK */

__device__ __forceinline__ float log_sigmoid(float x) {
    return fminf(x, 0.0f) - __logf(1.0f + __expf(-fabsf(x)));
}

__device__ __forceinline__ float segsq(float wx, float wy, float vx, float vy, float inv) {
    float t = (wx * vx + wy * vy) * inv;
    t = fminf(fmaxf(t, 0.0f), 1.0f);
    float dx = wx - t * vx;
    float dy = wy - t * vy;
    return dx * dx + dy * dy;
}

/* 5-float deterministic block reduction; result valid on tid 0 (in place) */
__device__ __forceinline__ void block_red5(float v[5], float* sbuf) {
    #pragma unroll
    for (int off = 32; off > 0; off >>= 1) {
        #pragma unroll
        for (int q = 0; q < 5; ++q) v[q] += __shfl_down(v[q], off);
    }
    const int lane = threadIdx.x & 63;
    const int wid  = threadIdx.x >> 6;
    __syncthreads();
    if (lane == 0) {
        #pragma unroll
        for (int q = 0; q < 5; ++q) sbuf[wid * 5 + q] = v[q];
    }
    __syncthreads();
    if (threadIdx.x == 0) {
        #pragma unroll
        for (int q = 0; q < 5; ++q) {
            float r = 0.0f;
            #pragma unroll
            for (int w = 0; w < NWAVE; ++w) r += sbuf[w * 5 + q];
            v[q] = r;
        }
    }
}

__global__ __launch_bounds__(PTHR)
void pair_kernel(const float* __restrict__ pred_reg,
                 const float* __restrict__ pred_obj,
                 const float* __restrict__ gt_pts,
                 const int*   __restrict__ stride_p,
                 unsigned* __restrict__ ccnt,
                 unsigned* __restrict__ smask,
                 unsigned long long* __restrict__ claims,
                 float4* __restrict__ pA,
                 int* __restrict__ arrival)
{
    const int pair = blockIdx.x;          // b*NG + g
    const int b    = pair >> 6;
    const int tid  = threadIdx.x;
    const int lane = tid & 63;
    const int wid  = tid >> 6;
    const float s  = (float)(*stride_p);

    __shared__ unsigned long long keys[CAP];   // (dist_bits<<16)|n — unique 48-bit keys
    __shared__ int      hist[PTHR];
    __shared__ float    sbuf[NWAVE * 5];
    __shared__ int      wsum[NWAVE];
    __shared__ unsigned mbits;
    __shared__ int      scnt, ccl, sd, sp;

    /* arrival counter for resolve_kernel (visible after this dispatch ends) */
    if (pair == 0 && tid == 0) *arrival = 0;

    /* pair-independent obj base: this block's slice of sum(-logsig(-x)) */
    float c_obj = 0.0f;
    if (tid < OBJ4_PER_BLK) {
        const float4 v = ((const float4*)pred_obj)[pair * OBJ4_PER_BLK + tid];
        c_obj = -log_sigmoid(-v.x) - log_sigmoid(-v.y)
                - log_sigmoid(-v.z) - log_sigmoid(-v.w);
    }

    const float* gp = gt_pts + (size_t)pair * 6;
    const float Ax = gp[0], Ay = gp[1];
    const float Bx = gp[2], By = gp[3];
    const float Cx = gp[4], Cy = gp[5];

    const float vABx = Bx - Ax, vABy = By - Ay;
    const float vBCx = Cx - Bx, vBCy = Cy - By;
    const float vCAx = Ax - Cx, vCAy = Ay - Cy;
    const float invAB = 1.0f / (vABx * vABx + vABy * vABy + 1e-9f);
    const float invBC = 1.0f / (vBCx * vBCx + vBCy * vBCy + 1e-9f);
    const float invCA = 1.0f / (vCAx * vCAx + vCAy * vCAy + 1e-9f);

    const float xmin = fminf(Ax, fminf(Bx, Cx)) - ETA;
    const float xmax = fmaxf(Ax, fmaxf(Bx, Cx)) + ETA;
    const float ymin = fminf(Ay, fminf(By, Cy)) - ETA;
    const float ymax = fmaxf(Ay, fmaxf(By, Cy)) + ETA;
    const float inv_sf = 1.0f / s;
    int j0 = max(0,      (int)floorf(xmin * inv_sf - 0.5f) - 1);
    int j1 = min(WW - 1, (int)ceilf (xmax * inv_sf - 0.5f) + 1);
    int i0 = max(0,      (int)floorf(ymin * inv_sf - 0.5f) - 1);
    int i1 = min(HH - 1, (int)ceilf (ymax * inv_sf - 0.5f) + 1);
    const int nbw = j1 - j0 + 1;
    const int nbh = i1 - i0 + 1;
    const int nb  = (nbw > 0 && nbh > 0) ? nbw * nbh : 0;

    if (tid == 0) { scnt = 0; ccl = 0; mbits = 0u; }
    __syncthreads();

    /* ---- bbox scan: collect positive cells ---- */
    for (int t = tid; t < nb; t += PTHR) {
        const int li = t / nbw;
        const int lj = t - li * nbw;
        const int i = i0 + li;
        const int j = j0 + lj;
        const float px = ((float)j + 0.5f) * s;
        const float py = ((float)i + 0.5f) * s;

        const float d1 = (px - Bx) * (Ay - By) - (Ax - Bx) * (py - By);
        const float d2 = (px - Cx) * (By - Cy) - (Bx - Cx) * (py - Cy);
        const float d3 = (px - Ax) * (Cy - Ay) - (Cx - Ax) * (py - Ay);
        const bool has_neg = (d1 < 0.0f) | (d2 < 0.0f) | (d3 < 0.0f);
        const bool has_pos = (d1 > 0.0f) | (d2 > 0.0f) | (d3 > 0.0f);
        const bool inside = !(has_neg && has_pos);

        float dsq = segsq(px - Ax, py - Ay, vABx, vABy, invAB);
        dsq = fminf(dsq, segsq(px - Bx, py - By, vBCx, vBCy, invBC));
        dsq = fminf(dsq, segsq(px - Cx, py - Cy, vCAx, vCAy, invCA));
        const float dist = sqrtf(dsq + 1e-12f);

        if (inside || dist <= ETA) {
            int slot = atomicAdd(&scnt, 1);
            if (slot < CAP) {
                const int n = i * WW + j;
                keys[slot] = (((unsigned long long)__float_as_uint(dist)) << 16) | (unsigned)n;
            }
        }
    }
    __syncthreads();

    const int M = min(scnt, CAP);
    unsigned long long T = INF64;

    if (M > KCAP) {
        /* exact 48-bit radix select of the KCAP-th smallest key */
        unsigned long long prefix = 0;
        int need = KCAP;
        for (int shift = 40; shift >= 0; shift -= 8) {
            hist[tid] = 0;
            __syncthreads();
            for (int t = tid; t < M; t += PTHR) {
                const unsigned long long k = keys[t];
                if ((k >> (shift + 8)) == prefix)
                    atomicAdd(&hist[(int)((k >> shift) & 0xFF)], 1);
            }
            __syncthreads();
            const int h = hist[tid];
            int incl = h;
            #pragma unroll
            for (int off = 1; off < 64; off <<= 1) {
                const int o = __shfl_up(incl, off);
                if (lane >= off) incl += o;
            }
            if (lane == 63) wsum[wid] = incl;
            __syncthreads();
            #pragma unroll
            for (int w = 0; w < NWAVE; ++w) if (w < wid) incl += wsum[w];
            const int excl = incl - h;
            if (excl < need && incl >= need) { sd = tid; sp = excl; }
            __syncthreads();
            prefix = (prefix << 8) | (unsigned)sd;
            need  -= sp;
            __syncthreads();
        }
        T = prefix;   // exactly KCAP keys <= T
    }

    /* ---- claim emit (+ segment mask) + reg loss ---- */
    float c_reg = 0.0f;
    for (int t = tid; t < M; t += PTHR) {
        const unsigned long long k = keys[t];
        if (k > T) continue;
        const int n = (int)(k & 0xFFFFull);

        const int slot = atomicAdd(&ccl, 1);
        if (slot < KCAP) {
            claims[(size_t)pair * KCAP + slot] =
                ((k >> 16) << 32) | (unsigned long long)(unsigned)n;
            atomicOr(&mbits, 1u << (n / SEGC));
        }

        const int i = n / WW;
        const int j = n - i * WW;
        const float ax = ((float)j + 0.5f) * s;
        const float ay = ((float)i + 0.5f) * s;

        const float g0x = (Ax - ax) * inv_sf, g0y = (Ay - ay) * inv_sf;
        const float g1x = (Bx - ax) * inv_sf, g1y = (By - ay) * inv_sf;
        const float g2x = (Cx - ax) * inv_sf, g2y = (Cy - ay) * inv_sf;

        const float* pr = pred_reg + (size_t)b * 6 * NCELL + n;
        const float p0x = pr[0 * NCELL], p0y = pr[1 * NCELL];
        const float p1x = pr[2 * NCELL], p1y = pr[3 * NCELL];
        const float p2x = pr[4 * NCELL], p2y = pr[5 * NCELL];

        c_reg += (p0x - g0x) * (p0x - g0x) + (p0y - g0y) * (p0y - g0y);

        const float d11 = sqrtf((p1x - g1x) * (p1x - g1x) + (p1y - g1y) * (p1y - g1y) + 1e-12f);
        const float d12 = sqrtf((p1x - g2x) * (p1x - g2x) + (p1y - g2y) * (p1y - g2y) + 1e-12f);
        const float d21 = sqrtf((p2x - g1x) * (p2x - g1x) + (p2y - g1y) * (p2y - g1y) + 1e-12f);
        const float d22 = sqrtf((p2x - g2x) * (p2x - g2x) + (p2y - g2y) * (p2y - g2y) + 1e-12f);

        c_reg += fminf(d11, d12) + fminf(d21, d22)
               + fminf(d11, d21) + fminf(d12, d22);
    }
    __syncthreads();   // ccl/mbits final; claim stores drained at barrier
    if (tid == 0) {
        ccnt[pair]  = (unsigned)min(ccl, KCAP);
        smask[pair] = mbits;
    }

    float v[5] = { c_reg, c_obj, 0.0f, 0.0f, 0.0f };
    block_red5(v, sbuf);
    if (tid == 0) pA[pair] = make_float4(v[0], v[1], 0.0f, 0.0f);
}

__global__ __launch_bounds__(PTHR)
void resolve_kernel(const float* __restrict__ pred_obj,
                    const float* __restrict__ pred_cls,
                    const int*   __restrict__ gt_lbl,
                    const unsigned* __restrict__ ccnt,
                    const unsigned* __restrict__ smask,
                    const unsigned long long* __restrict__ claims,
                    const float4* __restrict__ pA,
                    float4* __restrict__ pC,
                    int* __restrict__ arrival,
                    float* __restrict__ out)
{
    const int blk = blockIdx.x;
    const int b   = blk >> 5;               /* blk / SEGS */
    const int seg = blk & (SEGS - 1);
    const int n0  = seg * SEGC;
    const int tid = threadIdx.x;

    __shared__ unsigned long long cl[BCLAIM];   /* 48 KB: in-seg claims */
    __shared__ unsigned table[SEGC];            /* 4.5 KB: per-cell min */
    __shared__ int      cnts[NG];
    __shared__ unsigned msks[NG];
    __shared__ float    sbuf[NWAVE * 5];
    __shared__ int      ccl, islast;

    if (tid < NG) {
        cnts[tid] = (int)ccnt[b * NG + tid];
        msks[tid] = smask[b * NG + tid];
    }
    if (tid == 0) { ccl = 0; islast = 0; }
    for (int i = tid; i < SEGC; i += PTHR) table[i] = 0xFFFFFFFFu;
    __syncthreads();

    /* pass 1: mask-guided compaction of my-segment claims into LDS
       + exact dist_bits atomicMin. Only pairs whose bitmask includes
       this segment are scanned (~6 of 64). */
    const unsigned long long* bcl = claims + (size_t)b * BCLAIM;
    for (int p = 0; p < NG; ++p) {
        if (!((msks[p] >> seg) & 1u)) continue;       /* block-uniform skip */
        const int cnt = cnts[p];
        for (int r = tid; r < cnt; r += PTHR) {
            const unsigned long long e = bcl[p * KCAP + r];
            const int ln = (int)(e & 0xFFFFull) - n0;
            if ((unsigned)ln < (unsigned)SEGC) {
                const int i = atomicAdd(&ccl, 1);
                cl[i] = e | ((unsigned long long)p << 16);  /* stash g */
                atomicMin(&table[ln], (unsigned)(e >> 32));
            }
        }
    }
    __syncthreads();
    const int NC = ccl;

    /* pass 2a: mark dist-winners while table still holds dists */
    for (int i = tid; i < NC; i += PTHR) {
        const unsigned long long e = cl[i];
        const int ln = (int)(e & 0xFFFFull) - n0;
        if (table[ln] == (unsigned)(e >> 32)) cl[i] = e | TOPBIT;
    }
    __syncthreads();
    /* pass 2b: tie-break by g (g<64 < any dist bits since dist>=1e-6) */
    for (int i = tid; i < NC; i += PTHR) {
        const unsigned long long e = cl[i];
        if (e & TOPBIT) {
            const int ln = (int)(e & 0xFFFFull) - n0;
            atomicMin(&table[ln], (unsigned)((e >> 16) & 63ull));
        }
    }
    __syncthreads();

    /* pass 3: unique winners compute obj-correction, lse, picked */
    float v[5] = { 0.0f, 0.0f, 0.0f, 0.0f, 0.0f };
    const size_t bc = (size_t)b * NCLS * NCELL;
    for (int i = tid; i < NC; i += PTHR) {
        const unsigned long long e = cl[i];
        if (!(e & TOPBIT)) continue;
        const int n = (int)(e & 0xFFFFull);
        const int g = (int)((e >> 16) & 63ull);
        if (table[n - n0] != (unsigned)g) continue;

        const float x = pred_obj[b * NCELL + n];
        v[0] += (-POS_W * log_sigmoid(x)) + log_sigmoid(-x);

        const float* pc = pred_cls + bc + n;
        const float l0 = pc[0];
        const float l1 = pc[NCELL];
        const float l2 = pc[2 * NCELL];
        const float l3 = pc[3 * NCELL];
        const float m = fmaxf(fmaxf(l0, l1), fmaxf(l2, l3));
        v[1] += m + __logf(__expf(l0 - m) + __expf(l1 - m)
                         + __expf(l2 - m) + __expf(l3 - m));
        const int tgt = gt_lbl[b * NG + g];
        v[2] += (tgt == 0) ? l0 : (tgt == 1) ? l1 : (tgt == 2) ? l2 : l3;
    }
    block_red5(v, sbuf);

    if (tid == 0) {
        pC[blk] = make_float4(v[0], v[1], v[2], 0.0f);
        __threadfence();
        const int old = atomicAdd(arrival, 1);
        if (old == NB2 - 1) islast = 1;
    }
    __syncthreads();
    if (!islast) return;
    __threadfence();

    /* last-arriving block: deterministic final reduce (NBLK == PTHR == 256) */
    const float4 a = pA[tid];
    const float4 c = (tid < NB2) ? pC[tid] : make_float4(0.f, 0.f, 0.f, 0.f);
    float w[5] = { a.x, a.y, c.x, c.y, c.z };
    block_red5(w, sbuf);
    if (tid == 0) {
        out[0] = w[0];               /* reg */
        out[1] = w[1] + w[2];        /* obj base + obj corrections */
        out[2] = w[3] - w[4];        /* lse - picked */
    }
}

extern "C" void kernel_launch(void* const* d_in, const int* in_sizes, int n_in,
                              void* d_out, int out_size, void* d_ws, size_t ws_size,
                              hipStream_t stream) {
    const float* pred_reg = (const float*)d_in[0];
    const float* pred_obj = (const float*)d_in[1];
    const float* pred_cls = (const float*)d_in[2];
    const float* gt_pts   = (const float*)d_in[3];
    const int*   gt_lbl   = (const int*)d_in[4];
    const int*   stride_p = (const int*)d_in[5];
    float* out = (float*)d_out;

    char* ws = (char*)d_ws;
    int*      arrival = (int*)ws;
    unsigned* ccnt    = (unsigned*)(ws + WS_CCNT);
    unsigned* smask   = (unsigned*)(ws + WS_MASK);
    unsigned long long* claims = (unsigned long long*)(ws + WS_CLAIM);
    float4*   pA      = (float4*)(ws + WS_PA);
    float4*   pC      = (float4*)(ws + WS_PC);

    (void)in_sizes; (void)n_in; (void)ws_size; (void)out_size;

    hipLaunchKernelGGL(pair_kernel, dim3(NBLK), dim3(PTHR), 0, stream,
                       pred_reg, pred_obj, gt_pts, stride_p,
                       ccnt, smask, claims, pA, arrival);
    hipLaunchKernelGGL(resolve_kernel, dim3(NB2), dim3(PTHR), 0, stream,
                       pred_obj, pred_cls, gt_lbl, ccnt, smask, claims, pA,
                       pC, arrival, out);
}

// Round 5
// 20.560 us; speedup vs baseline: 1.4002x; 1.1342x over previous
//
#include <hip/hip_runtime.h>
#include <stdint.h>

#define ETA    3.0f
#define KCAP   96
#define POS_W  1.2f
#define NG     64
#define BATCH  4
#define HH     192
#define WW     192
#define NCELL  (HH*WW)
#define NCLS   4
#define CAP    4096
#define PTHR   256
#define NWAVE  4
#define NBLK   (BATCH*NG)          /* 256 pair blocks */
#define SEGS   16                  /* cell segments per batch in resolve */
#define NB2    (BATCH*SEGS)        /* 64 resolve blocks */
#define SEGC   (NCELL/SEGS)        /* 2304 cells per segment */
#define BCLAIM (NG*KCAP)           /* 6144 claim slots per batch */
#define INF64  0xFFFFFFFFFFFFFFFFull
#define TOPBIT 0x8000000000000000ull

/* ws layout (NO host-side init; arrival init'd by pair_kernel block 0):
   [0]        arrival int
   [WS_CCNT]  ccnt  u32[NBLK]           per-pair claim counts
   [WS_CLAIM] claims u64[NBLK*KCAP]     (dist_bits<<32)|n   (16B aligned)
   [WS_PA]    pA float2[NBLK]           (reg, obj_base) partials
   [WS_PC]    pC float4[NB2]            (obj_corr, lse, picked) partials */
#define WS_CCNT  16
#define WS_CLAIM (WS_CCNT + NBLK*4)          /* 1040, 16-aligned */
#define WS_PA    (WS_CLAIM + NBLK*KCAP*8)    /* 197648, 16-aligned */
#define WS_PC    (WS_PA + NBLK*8)

#define OBJ4_PER_BLK 144   /* (B*NCELL floats / 4) / NBLK */

__device__ __forceinline__ float log_sigmoid(float x) {
    return fminf(x, 0.0f) - __logf(1.0f + __expf(-fabsf(x)));
}

__device__ __forceinline__ float segsq(float wx, float wy, float vx, float vy, float inv) {
    float t = (wx * vx + wy * vy) * inv;
    t = fminf(fmaxf(t, 0.0f), 1.0f);
    float dx = wx - t * vx;
    float dy = wy - t * vy;
    return dx * dx + dy * dy;
}

/* deterministic block reductions; result valid on tid 0 (in place) */
template <int NQ>
__device__ __forceinline__ void block_red(float v[NQ], float* sbuf) {
    #pragma unroll
    for (int off = 32; off > 0; off >>= 1) {
        #pragma unroll
        for (int q = 0; q < NQ; ++q) v[q] += __shfl_down(v[q], off);
    }
    const int lane = threadIdx.x & 63;
    const int wid  = threadIdx.x >> 6;
    __syncthreads();
    if (lane == 0) {
        #pragma unroll
        for (int q = 0; q < NQ; ++q) sbuf[wid * NQ + q] = v[q];
    }
    __syncthreads();
    if (threadIdx.x == 0) {
        #pragma unroll
        for (int q = 0; q < NQ; ++q) {
            float r = 0.0f;
            #pragma unroll
            for (int w = 0; w < NWAVE; ++w) r += sbuf[w * NQ + q];
            v[q] = r;
        }
    }
}

__global__ __launch_bounds__(PTHR)
void pair_kernel(const float* __restrict__ pred_reg,
                 const float* __restrict__ pred_obj,
                 const float* __restrict__ gt_pts,
                 const int*   __restrict__ stride_p,
                 unsigned* __restrict__ ccnt,
                 unsigned long long* __restrict__ claims,
                 float2* __restrict__ pA,
                 int* __restrict__ arrival)
{
    const int pair = blockIdx.x;          // b*NG + g
    const int b    = pair >> 6;
    const int tid  = threadIdx.x;
    const int lane = tid & 63;
    const int wid  = tid >> 6;
    const float s  = (float)(*stride_p);

    __shared__ unsigned long long keys[CAP];   // (dist_bits<<16)|n — unique 48-bit keys
    __shared__ int   hist[PTHR];
    __shared__ float sbuf[NWAVE * 5];
    __shared__ int   wsum[NWAVE];
    __shared__ int   scnt, ccl, sd, sp;

    /* arrival counter for resolve_kernel (visible after this dispatch ends) */
    if (pair == 0 && tid == 0) *arrival = 0;

    /* pair-independent obj base: this block's slice of sum(-logsig(-x)) */
    float c_obj = 0.0f;
    if (tid < OBJ4_PER_BLK) {
        const float4 v = ((const float4*)pred_obj)[pair * OBJ4_PER_BLK + tid];
        c_obj = -log_sigmoid(-v.x) - log_sigmoid(-v.y)
                - log_sigmoid(-v.z) - log_sigmoid(-v.w);
    }

    const float* gp = gt_pts + (size_t)pair * 6;
    const float Ax = gp[0], Ay = gp[1];
    const float Bx = gp[2], By = gp[3];
    const float Cx = gp[4], Cy = gp[5];

    const float vABx = Bx - Ax, vABy = By - Ay;
    const float vBCx = Cx - Bx, vBCy = Cy - By;
    const float vCAx = Ax - Cx, vCAy = Ay - Cy;
    const float invAB = 1.0f / (vABx * vABx + vABy * vABy + 1e-9f);
    const float invBC = 1.0f / (vBCx * vBCx + vBCy * vBCy + 1e-9f);
    const float invCA = 1.0f / (vCAx * vCAx + vCAy * vCAy + 1e-9f);

    const float xmin = fminf(Ax, fminf(Bx, Cx)) - ETA;
    const float xmax = fmaxf(Ax, fmaxf(Bx, Cx)) + ETA;
    const float ymin = fminf(Ay, fminf(By, Cy)) - ETA;
    const float ymax = fmaxf(Ay, fmaxf(By, Cy)) + ETA;
    const float inv_sf = 1.0f / s;
    int j0 = max(0,      (int)floorf(xmin * inv_sf - 0.5f) - 1);
    int j1 = min(WW - 1, (int)ceilf (xmax * inv_sf - 0.5f) + 1);
    int i0 = max(0,      (int)floorf(ymin * inv_sf - 0.5f) - 1);
    int i1 = min(HH - 1, (int)ceilf (ymax * inv_sf - 0.5f) + 1);
    const int nbw = j1 - j0 + 1;
    const int nbh = i1 - i0 + 1;
    const int nb  = (nbw > 0 && nbh > 0) ? nbw * nbh : 0;

    if (tid == 0) { scnt = 0; ccl = 0; }
    __syncthreads();

    /* ---- bbox scan: collect positive cells ---- */
    for (int t = tid; t < nb; t += PTHR) {
        const int li = t / nbw;
        const int lj = t - li * nbw;
        const int i = i0 + li;
        const int j = j0 + lj;
        const float px = ((float)j + 0.5f) * s;
        const float py = ((float)i + 0.5f) * s;

        const float d1 = (px - Bx) * (Ay - By) - (Ax - Bx) * (py - By);
        const float d2 = (px - Cx) * (By - Cy) - (Bx - Cx) * (py - Cy);
        const float d3 = (px - Ax) * (Cy - Ay) - (Cx - Ax) * (py - Ay);
        const bool has_neg = (d1 < 0.0f) | (d2 < 0.0f) | (d3 < 0.0f);
        const bool has_pos = (d1 > 0.0f) | (d2 > 0.0f) | (d3 > 0.0f);
        const bool inside = !(has_neg && has_pos);

        float dsq = segsq(px - Ax, py - Ay, vABx, vABy, invAB);
        dsq = fminf(dsq, segsq(px - Bx, py - By, vBCx, vBCy, invBC));
        dsq = fminf(dsq, segsq(px - Cx, py - Cy, vCAx, vCAy, invCA));
        const float dist = sqrtf(dsq + 1e-12f);

        if (inside || dist <= ETA) {
            int slot = atomicAdd(&scnt, 1);
            if (slot < CAP) {
                const int n = i * WW + j;
                keys[slot] = (((unsigned long long)__float_as_uint(dist)) << 16) | (unsigned)n;
            }
        }
    }
    __syncthreads();

    const int M = min(scnt, CAP);
    unsigned long long T = INF64;

    if (M > KCAP) {
        /* exact 48-bit radix select of the KCAP-th smallest key */
        unsigned long long prefix = 0;
        int need = KCAP;
        for (int shift = 40; shift >= 0; shift -= 8) {
            hist[tid] = 0;
            __syncthreads();
            for (int t = tid; t < M; t += PTHR) {
                const unsigned long long k = keys[t];
                if ((k >> (shift + 8)) == prefix)
                    atomicAdd(&hist[(int)((k >> shift) & 0xFF)], 1);
            }
            __syncthreads();
            const int h = hist[tid];
            int incl = h;
            #pragma unroll
            for (int off = 1; off < 64; off <<= 1) {
                const int o = __shfl_up(incl, off);
                if (lane >= off) incl += o;
            }
            if (lane == 63) wsum[wid] = incl;
            __syncthreads();
            #pragma unroll
            for (int w = 0; w < NWAVE; ++w) if (w < wid) incl += wsum[w];
            const int excl = incl - h;
            if (excl < need && incl >= need) { sd = tid; sp = excl; }
            __syncthreads();
            prefix = (prefix << 8) | (unsigned)sd;
            need  -= sp;
            __syncthreads();
        }
        T = prefix;   // exactly KCAP keys <= T
    }

    /* ---- claim emit + reg loss (resolution deferred to resolve_kernel) ---- */
    float c_reg = 0.0f;
    for (int t = tid; t < M; t += PTHR) {
        const unsigned long long k = keys[t];
        if (k > T) continue;
        const int n = (int)(k & 0xFFFFull);

        const int slot = atomicAdd(&ccl, 1);
        if (slot < KCAP)
            claims[(size_t)pair * KCAP + slot] =
                ((k >> 16) << 32) | (unsigned long long)(unsigned)n;

        const int i = n / WW;
        const int j = n - i * WW;
        const float ax = ((float)j + 0.5f) * s;
        const float ay = ((float)i + 0.5f) * s;

        const float g0x = (Ax - ax) * inv_sf, g0y = (Ay - ay) * inv_sf;
        const float g1x = (Bx - ax) * inv_sf, g1y = (By - ay) * inv_sf;
        const float g2x = (Cx - ax) * inv_sf, g2y = (Cy - ay) * inv_sf;

        const float* pr = pred_reg + (size_t)b * 6 * NCELL + n;
        const float p0x = pr[0 * NCELL], p0y = pr[1 * NCELL];
        const float p1x = pr[2 * NCELL], p1y = pr[3 * NCELL];
        const float p2x = pr[4 * NCELL], p2y = pr[5 * NCELL];

        c_reg += (p0x - g0x) * (p0x - g0x) + (p0y - g0y) * (p0y - g0y);

        const float d11 = sqrtf((p1x - g1x) * (p1x - g1x) + (p1y - g1y) * (p1y - g1y) + 1e-12f);
        const float d12 = sqrtf((p1x - g2x) * (p1x - g2x) + (p1y - g2y) * (p1y - g2y) + 1e-12f);
        const float d21 = sqrtf((p2x - g1x) * (p2x - g1x) + (p2y - g1y) * (p2y - g1y) + 1e-12f);
        const float d22 = sqrtf((p2x - g2x) * (p2x - g2x) + (p2y - g2y) * (p2y - g2y) + 1e-12f);

        c_reg += fminf(d11, d12) + fminf(d21, d22)
               + fminf(d11, d21) + fminf(d12, d22);
    }
    __syncthreads();   // ccl final; claim stores drained at barrier
    if (tid == 0) ccnt[pair] = (unsigned)min(ccl, KCAP);

    float v[2] = { c_reg, c_obj };
    block_red<2>(v, sbuf);
    if (tid == 0) pA[pair] = make_float2(v[0], v[1]);
}

__global__ __launch_bounds__(PTHR)
void resolve_kernel(const float* __restrict__ pred_obj,
                    const float* __restrict__ pred_cls,
                    const int*   __restrict__ gt_lbl,
                    const unsigned* __restrict__ ccnt,
                    const unsigned long long* __restrict__ claims,
                    const float2* __restrict__ pA,
                    float4* __restrict__ pC,
                    int* __restrict__ arrival,
                    float* __restrict__ out)
{
    const int blk = blockIdx.x;
    const int b   = blk >> 4;               /* blk / SEGS */
    const int seg = blk & (SEGS - 1);
    const int n0  = seg * SEGC;
    const int tid = threadIdx.x;

    __shared__ unsigned long long cl[BCLAIM];   /* 48 KB: in-seg claims */
    __shared__ unsigned table[SEGC];            /* 9 KB: per-cell min */
    __shared__ int   cnts[NG];
    __shared__ float sbuf[NWAVE * 5];
    __shared__ int   ccl, islast;

    if (tid < NG) cnts[tid] = (int)ccnt[b * NG + tid];
    if (tid == 0) { ccl = 0; islast = 0; }
    for (int i = tid; i < SEGC; i += PTHR) table[i] = 0xFFFFFFFFu;
    __syncthreads();

    /* pass 1: vectorized compaction of my-segment claims into LDS + exact
       dist_bits atomicMin. KCAP even + 16B-aligned base => a ulonglong2
       never straddles a pair boundary; per-element count guards keep it
       exact. 12 full-width coalesced rounds (was 24 scalar). */
    const unsigned long long* bcl = claims + (size_t)b * BCLAIM;
    #pragma unroll 1
    for (int q = tid; q < BCLAIM / 2; q += PTHR) {
        const int sIdx = 2 * q;
        const int pg = sIdx / KCAP;
        const int r  = sIdx - pg * KCAP;
        const int cnt = cnts[pg];
        if (r >= cnt) continue;
        const ulonglong2 e2 = ((const ulonglong2*)bcl)[q];
        {
            const unsigned long long e = e2.x;
            const int ln = (int)(e & 0xFFFFull) - n0;
            if ((unsigned)ln < (unsigned)SEGC) {
                const int i = atomicAdd(&ccl, 1);
                cl[i] = e | ((unsigned long long)pg << 16);  /* stash g */
                atomicMin(&table[ln], (unsigned)(e >> 32));
            }
        }
        if (r + 1 < cnt) {
            const unsigned long long e = e2.y;
            const int ln = (int)(e & 0xFFFFull) - n0;
            if ((unsigned)ln < (unsigned)SEGC) {
                const int i = atomicAdd(&ccl, 1);
                cl[i] = e | ((unsigned long long)pg << 16);
                atomicMin(&table[ln], (unsigned)(e >> 32));
            }
        }
    }
    __syncthreads();
    const int NC = ccl;

    /* pass 2a: mark dist-winners while table still holds dists */
    for (int i = tid; i < NC; i += PTHR) {
        const unsigned long long e = cl[i];
        const int ln = (int)(e & 0xFFFFull) - n0;
        if (table[ln] == (unsigned)(e >> 32)) cl[i] = e | TOPBIT;
    }
    __syncthreads();
    /* pass 2b: tie-break by g (g<64 < any dist bits since dist>=1e-6) */
    for (int i = tid; i < NC; i += PTHR) {
        const unsigned long long e = cl[i];
        if (e & TOPBIT) {
            const int ln = (int)(e & 0xFFFFull) - n0;
            atomicMin(&table[ln], (unsigned)((e >> 16) & 63ull));
        }
    }
    __syncthreads();

    /* pass 3: unique winners compute obj-correction, lse, picked */
    float v[3] = { 0.0f, 0.0f, 0.0f };
    const size_t bc = (size_t)b * NCLS * NCELL;
    for (int i = tid; i < NC; i += PTHR) {
        const unsigned long long e = cl[i];
        if (!(e & TOPBIT)) continue;
        const int n = (int)(e & 0xFFFFull);
        const int g = (int)((e >> 16) & 63ull);
        if (table[n - n0] != (unsigned)g) continue;

        const float x = pred_obj[b * NCELL + n];
        v[0] += (-POS_W * log_sigmoid(x)) + log_sigmoid(-x);

        const float* pc = pred_cls + bc + n;
        const float l0 = pc[0];
        const float l1 = pc[NCELL];
        const float l2 = pc[2 * NCELL];
        const float l3 = pc[3 * NCELL];
        const float m = fmaxf(fmaxf(l0, l1), fmaxf(l2, l3));
        v[1] += m + __logf(__expf(l0 - m) + __expf(l1 - m)
                         + __expf(l2 - m) + __expf(l3 - m));
        const int tgt = gt_lbl[b * NG + g];
        v[2] += (tgt == 0) ? l0 : (tgt == 1) ? l1 : (tgt == 2) ? l2 : l3;
    }
    block_red<3>(v, sbuf);

    if (tid == 0) {
        pC[blk] = make_float4(v[0], v[1], v[2], 0.0f);
        __threadfence();
        const int old = atomicAdd(arrival, 1);
        if (old == NB2 - 1) islast = 1;
    }
    __syncthreads();
    if (!islast) return;
    __threadfence();

    /* last-arriving block: deterministic final reduce (NBLK == PTHR == 256) */
    const float2 a = pA[tid];
    const float4 c = (tid < NB2) ? pC[tid] : make_float4(0.f, 0.f, 0.f, 0.f);
    float w[5] = { a.x, a.y, c.x, c.y, c.z };
    block_red<5>(w, sbuf);
    if (tid == 0) {
        out[0] = w[0];               /* reg */
        out[1] = w[1] + w[2];        /* obj base + obj corrections */
        out[2] = w[3] - w[4];        /* lse - picked */
    }
}

extern "C" void kernel_launch(void* const* d_in, const int* in_sizes, int n_in,
                              void* d_out, int out_size, void* d_ws, size_t ws_size,
                              hipStream_t stream) {
    const float* pred_reg = (const float*)d_in[0];
    const float* pred_obj = (const float*)d_in[1];
    const float* pred_cls = (const float*)d_in[2];
    const float* gt_pts   = (const float*)d_in[3];
    const int*   gt_lbl   = (const int*)d_in[4];
    const int*   stride_p = (const int*)d_in[5];
    float* out = (float*)d_out;

    char* ws = (char*)d_ws;
    int*      arrival = (int*)ws;
    unsigned* ccnt    = (unsigned*)(ws + WS_CCNT);
    unsigned long long* claims = (unsigned long long*)(ws + WS_CLAIM);
    float2*   pA      = (float2*)(ws + WS_PA);
    float4*   pC      = (float4*)(ws + WS_PC);

    (void)in_sizes; (void)n_in; (void)ws_size; (void)out_size;

    hipLaunchKernelGGL(pair_kernel, dim3(NBLK), dim3(PTHR), 0, stream,
                       pred_reg, pred_obj, gt_pts, stride_p,
                       ccnt, claims, pA, arrival);
    hipLaunchKernelGGL(resolve_kernel, dim3(NB2), dim3(PTHR), 0, stream,
                       pred_obj, pred_cls, gt_lbl, ccnt, claims, pA,
                       pC, arrival, out);
}